// Round 2
// baseline (2746.228 us; speedup 1.0000x reference)
//
#include <hip/hip_runtime.h>

typedef float  f32x4  __attribute__((ext_vector_type(4)));
typedef short  bf16x8 __attribute__((ext_vector_type(8)));
typedef unsigned short u16x4 __attribute__((ext_vector_type(4)));

#define MFMA16(a,b,c) __builtin_amdgcn_mfma_f32_16x16x32_bf16((a),(b),(c),0,0,0)

__device__ __forceinline__ unsigned short f2bf(float f){
  unsigned u = __float_as_uint(f);
  u += 0x7fffu + ((u>>16)&1u);            // RNE
  return (unsigned short)(u>>16);
}
__device__ __forceinline__ float bf2f(unsigned short u){
  return __uint_as_float(((unsigned)u)<<16);
}
__device__ __forceinline__ float sigm(float x){
  return __fdividef(1.f, 1.f + __expf(-x));
}
__device__ __forceinline__ float tanhfast(float x){
  return 1.f - __fdividef(2.f, __expf(2.f*x) + 1.f);
}
__device__ __forceinline__ float dot128(const float* __restrict__ w, const float* s){
  float a0=0.f,a1=0.f,a2=0.f,a3=0.f;
  #pragma unroll
  for (int e=0;e<32;++e){
    f32x4 w4 = *(const f32x4*)(w + (e<<2));
    f32x4 x4 = *(const f32x4*)(s + (e<<2));
    a0 = fmaf(w4[0],x4[0],a0); a1 = fmaf(w4[1],x4[1],a1);
    a2 = fmaf(w4[2],x4[2],a2); a3 = fmaf(w4[3],x4[3],a3);
  }
  return (a0+a1)+(a2+a3);
}

// ---------------- prep 1: weights f32->bf16 + mask dtype probe ----------------
__global__ void prep_weights(const float* __restrict__ wih, const float* __restrict__ whh,
                             const float* __restrict__ wks, const float* __restrict__ wvs,
                             const int* __restrict__ mask_i,
                             unsigned short* __restrict__ dst, int* __restrict__ flags){
  const int tid = blockIdx.x*256 + threadIdx.x;     // 512*256 = 131072 exactly
  if (tid < 49152)        dst[tid] = f2bf(wih[tid]);
  else if (tid < 98304)   dst[tid] = f2bf(whh[tid-49152]);
  else if (tid < 114688)  dst[tid] = f2bf(wks[tid-98304]);
  else                    dst[tid] = f2bf(wvs[tid-114688]);
  if (blockIdx.x==0 && threadIdx.x==0){
    int bytemode = 0;
    for (int i=0;i<64;++i){ unsigned v = (unsigned)mask_i[i]; if (v > 1u) bytemode = 1; }
    flags[0] = bytemode;
  }
}

// ---------------- prep 2: q = src @ w_qs^T  (8192 x 128) ----------------
__global__ void prep_q(const float* __restrict__ src, const float* __restrict__ wqs,
                       float* __restrict__ q_ws){
  __shared__ __align__(16) float s_lds[32*128];
  const int t = threadIdx.x;                  // 128 threads
  const size_t r0 = (size_t)blockIdx.x * 32;
  for (int it=0; it<32; ++it){
    const int idx = t + it*128;
    s_lds[idx] = src[r0*128 + idx];
  }
  __syncthreads();
  const float* wr = wqs + t*128;
  for (int rg=0; rg<8; ++rg){
    float a0=0.f,a1=0.f,a2=0.f,a3=0.f;
    #pragma unroll
    for (int e=0;e<32;++e){
      f32x4 w4 = *(const f32x4*)(wr + (e<<2));
      f32x4 x0 = *(const f32x4*)&s_lds[(rg*4+0)*128 + (e<<2)];
      f32x4 x1 = *(const f32x4*)&s_lds[(rg*4+1)*128 + (e<<2)];
      f32x4 x2 = *(const f32x4*)&s_lds[(rg*4+2)*128 + (e<<2)];
      f32x4 x3 = *(const f32x4*)&s_lds[(rg*4+3)*128 + (e<<2)];
      #pragma unroll
      for (int k=0;k<4;++k){
        a0 = fmaf(w4[k],x0[k],a0); a1 = fmaf(w4[k],x1[k],a1);
        a2 = fmaf(w4[k],x2[k],a2); a3 = fmaf(w4[k],x3[k],a3);
      }
    }
    q_ws[(r0+rg*4+0)*128 + t] = a0;
    q_ws[(r0+rg*4+1)*128 + t] = a1;
    q_ws[(r0+rg*4+2)*128 + t] = a2;
    q_ws[(r0+rg*4+3)*128 + t] = a3;
  }
}

// ---------------- main fused kernel: 4 sources per block ----------------
// LDS layout (52240 B -> 3 blocks/CU):
//   [0)      bufA u16[64][128]  x -> seq      | epilogue: ep1 f32[4][128], ep2 f32[4][128]
//   [16384)  bufB u16[64][128]  h -> k
//   [32768)  bufC u16[64][128]  v             | epilogue: srce f32[4][128]
//   [49152)  q    f32[128]
//   [49664)  sc   f32[2][64]
//   [50176)  ao   f32[4][128]
//   [52224)  hflag int[4]
__global__ __launch_bounds__(256, 3) void cawn_main(
    const float* __restrict__ src, const float* __restrict__ ngh,
    const float* __restrict__ hid, const int* __restrict__ mask_i,
    const float* __restrict__ bih, const float* __restrict__ bhh,
    const float* __restrict__ fcw, const float* __restrict__ fcb,
    const float* __restrict__ lng, const float* __restrict__ lnb,
    const float* __restrict__ m1w, const float* __restrict__ m1b,
    const float* __restrict__ m2w, const float* __restrict__ m2b,
    const unsigned short* __restrict__ wihb, const unsigned short* __restrict__ whhb,
    const unsigned short* __restrict__ wksb, const unsigned short* __restrict__ wvsb,
    const float* __restrict__ q_ws, const int* __restrict__ flags,
    float* __restrict__ out)
{
  __shared__ __align__(16) char smem[52240];
  unsigned short* bufA = (unsigned short*)smem;
  unsigned short* bufB = (unsigned short*)(smem + 16384);
  unsigned short* bufC = (unsigned short*)(smem + 32768);
  float* q_lds = (float*)(smem + 49152);
  float* sc    = (float*)(smem + 49664);
  float* ao    = (float*)(smem + 50176);
  int*   hflag = (int*)  (smem + 52224);

  const int t    = threadIdx.x;
  const int wv   = t >> 6;
  const int lane = t & 63;
  const int l15  = lane & 15;
  const int lgrp = lane >> 4;
  const int gsrc0 = blockIdx.x * 4;
  const int mask_mode = flags[0];
  const int rowl = (wv<<4) + l15;        // this lane's row in MFMA phases
  const int rswz = (rowl&7)<<3;
  const f32x4 z4 = {0.f,0.f,0.f,0.f};

  for (int sl=0; sl<4; ++sl){
    const int gsrc = gsrc0 + sl;
    const size_t base = (size_t)gsrc * 8192;

    // ---- stage x,h : f32 global -> bf16 LDS (XOR-swizzled rows) ----
    bool hnzl = false;
    #pragma unroll
    for (int it=0; it<8; ++it){
      const int f4  = t + (it<<8);
      const int m   = f4 >> 5;
      const int col = (f4 & 31) << 2;
      f32x4 vx = *(const f32x4*)(ngh + base + (f4<<2));
      f32x4 vh = *(const f32x4*)(hid + base + (f4<<2));
      hnzl = hnzl || (vh[0]!=0.f)||(vh[1]!=0.f)||(vh[2]!=0.f)||(vh[3]!=0.f);
      const int idx = (m<<7) + (col ^ ((m&7)<<3));
      u16x4 px, ph;
      px[0]=f2bf(vx[0]); px[1]=f2bf(vx[1]); px[2]=f2bf(vx[2]); px[3]=f2bf(vx[3]);
      ph[0]=f2bf(vh[0]); ph[1]=f2bf(vh[1]); ph[2]=f2bf(vh[2]); ph[3]=f2bf(vh[3]);
      *(u16x4*)&bufA[idx] = px;
      *(u16x4*)&bufB[idx] = ph;
    }
    if (t < 128) q_lds[t] = q_ws[(size_t)gsrc*128 + t];
    { unsigned long long b = __ballot((int)hnzl); if (lane==0) hflag[wv] = (b!=0ull)?1:0; }
    __syncthreads();                                  // (1)
    const int hnz = hflag[0] | hflag[1] | hflag[2] | hflag[3];

    // ---- GRU: wave owns rows [wv*16, wv*16+16); fused elementwise per 16-col tile ----
    bf16x8 ax[4], ah[4];
    #pragma unroll
    for (int kb=0;kb<4;++kb)
      ax[kb] = *(const bf16x8*)&bufA[(rowl<<7) + (((kb<<5)+(lgrp<<3)) ^ rswz)];
    if (hnz){
      #pragma unroll
      for (int kb=0;kb<4;++kb)
        ah[kb] = *(const bf16x8*)&bufB[(rowl<<7) + (((kb<<5)+(lgrp<<3)) ^ rswz)];
    }
    #pragma unroll
    for (int c=0;c<8;++c){
      const int cb = c<<4;
      f32x4 ar=z4, az=z4, an=z4, anh=z4;
      #pragma unroll
      for (int kb=0;kb<4;++kb){
        const int ko = (kb<<5)+(lgrp<<3);
        bf16x8 wr_ = *(const bf16x8*)(wihb + ((cb    +l15)<<7) + ko);
        bf16x8 wz_ = *(const bf16x8*)(wihb + ((128+cb+l15)<<7) + ko);
        bf16x8 wn_ = *(const bf16x8*)(wihb + ((256+cb+l15)<<7) + ko);
        ar = MFMA16(wr_, ax[kb], ar);
        az = MFMA16(wz_, ax[kb], az);
        an = MFMA16(wn_, ax[kb], an);
      }
      if (hnz){
        #pragma unroll
        for (int kb=0;kb<4;++kb){
          const int ko = (kb<<5)+(lgrp<<3);
          bf16x8 ur_ = *(const bf16x8*)(whhb + ((cb    +l15)<<7) + ko);
          bf16x8 uz_ = *(const bf16x8*)(whhb + ((128+cb+l15)<<7) + ko);
          bf16x8 un_ = *(const bf16x8*)(whhb + ((256+cb+l15)<<7) + ko);
          ar  = MFMA16(ur_, ah[kb], ar);
          az  = MFMA16(uz_, ah[kb], az);
          anh = MFMA16(un_, ah[kb], anh);
        }
      }
      const int colb = cb + (lgrp<<2);
      const f32x4 bir = *(const f32x4*)(bih+colb);
      const f32x4 biz = *(const f32x4*)(bih+128+colb);
      const f32x4 bin = *(const f32x4*)(bih+256+colb);
      const f32x4 bhr = *(const f32x4*)(bhh+colb);
      const f32x4 bhz = *(const f32x4*)(bhh+128+colb);
      const f32x4 bhn = *(const f32x4*)(bhh+256+colb);
      const int eidx = (rowl<<7) + (colb ^ rswz);
      const u16x4 hv = *(const u16x4*)&bufB[eidx];
      u16x4 sq;
      #pragma unroll
      for (int i=0;i<4;++i){
        const float rv = sigm(ar[i] + bir[i] + bhr[i]);
        const float zv = sigm(az[i] + biz[i] + bhz[i]);
        const float nv = tanhfast(an[i] + bin[i] + rv*(anh[i] + bhn[i]));
        sq[i] = f2bf((1.f - zv)*nv + zv*bf2f(hv[i]));
      }
      *(u16x4*)&bufA[eidx] = sq;
    }

    // ---- K/V projections (same wave-private rows) ----
    bf16x8 as_[4];
    #pragma unroll
    for (int kb=0;kb<4;++kb)
      as_[kb] = *(const bf16x8*)&bufA[(rowl<<7) + (((kb<<5)+(lgrp<<3)) ^ rswz)];
    #pragma unroll
    for (int c=0;c<8;++c){
      const int cb = c<<4;
      f32x4 akk=z4, avv=z4;
      #pragma unroll
      for (int kb=0;kb<4;++kb){
        const int ko = (kb<<5)+(lgrp<<3);
        bf16x8 wk_ = *(const bf16x8*)(wksb + ((cb+l15)<<7) + ko);
        bf16x8 wv_ = *(const bf16x8*)(wvsb + ((cb+l15)<<7) + ko);
        akk = MFMA16(wk_, as_[kb], akk);
        avv = MFMA16(wv_, as_[kb], avv);
      }
      const int colb = cb + (lgrp<<2);
      const int eidx = (rowl<<7) + (colb ^ rswz);
      u16x4 kk, vv;
      #pragma unroll
      for (int i=0;i<4;++i){ kk[i]=f2bf(akk[i]); vv[i]=f2bf(avv[i]); }
      *(u16x4*)&bufB[eidx] = kk;
      *(u16x4*)&bufC[eidx] = vv;
    }
    __syncthreads();                                  // (2)

    // ---- scores + softmax: wave w -> head w&1, lane = neighbor j (waves 2,3 redundant) ----
    {
      const int hh = wv & 1;
      float acc = 0.f;
      #pragma unroll
      for (int c8=0;c8<8;++c8){
        const int cb = (hh<<6)+(c8<<3);
        bf16x8 kc = *(const bf16x8*)&bufB[(lane<<7) + (cb ^ ((lane&7)<<3))];
        #pragma unroll
        for (int u=0;u<8;++u)
          acc = fmaf(bf2f((unsigned short)kc[u]), q_lds[cb+u], acc);
      }
      bool msk;
      if (mask_mode == 0) msk = (mask_i[(size_t)gsrc*64 + lane] != 0);
      else                msk = (((const unsigned char*)mask_i)[(size_t)gsrc*64 + lane] != 0);
      float s = msk ? -1e10f : acc*0.125f;
      float mx = s;
      #pragma unroll
      for (int o=32;o>=1;o>>=1) mx = fmaxf(mx, __shfl_xor(mx,o));
      const float e = __expf(s - mx);
      float sum = e;
      #pragma unroll
      for (int o=32;o>=1;o>>=1) sum += __shfl_xor(sum,o);
      if (wv < 2) sc[(hh<<6)+lane] = __fdividef(e, sum);
    }
    __syncthreads();                                  // (3)

    // ---- PV: all 256 threads; lane pair splits the j-range, shfl combine ----
    {
      const int hh   = (t>>6)&1;
      const int dd   = ((t>>7)<<5) + ((t>>1)&31);
      const int half = t & 1;
      const int col  = (hh<<6) + dd;
      float acc = 0.f;
      #pragma unroll
      for (int j0=0;j0<32;++j0){
        const int j = (half<<5) + j0;
        acc = fmaf(sc[(hh<<6)+j], bf2f(bufC[(j<<7) + (col ^ ((j&7)<<3))]), acc);
      }
      acc += __shfl_xor(acc, 1);
      if (!half) ao[(sl<<7) + col] = acc;
    }
    // no barrier: next stage writes only bufA/bufB/q; bufC & sc next written after (1)/(2)
  }
  __syncthreads();

  // ---------------- epilogue (overlays: ep1/ep2 on bufA, srce on bufC) ----------------
  float* ep1  = (float*)smem;            // [4][128]
  float* ep2  = (float*)(smem + 2048);   // [4][128]
  float* srce = (float*)(smem + 32768);  // [4][128]
  #pragma unroll
  for (int i=0;i<2;++i){
    const int idx = t + (i<<8);
    srce[idx] = src[(size_t)gsrc0*128 + idx];
  }
  __syncthreads();

  const int d  = t & 127;
  const int sh = (t >> 7) << 1;
  #pragma unroll
  for (int si=0; si<2; ++si){
    const int s = sh + si;
    ep1[s*128+d] = fcb[d] + dot128(fcw + d*128, ao + s*128) + srce[s*128+d];
  }
  __syncthreads();
  {
    const int s = wv;   // wave wv normalizes source wv
    const float v0 = ep1[s*128+lane], v1 = ep1[s*128+64+lane];
    float sum = v0+v1, sq_ = v0*v0 + v1*v1;
    #pragma unroll
    for (int o=32;o>=1;o>>=1){ sum += __shfl_xor(sum,o); sq_ += __shfl_xor(sq_,o); }
    const float mu  = sum * 0.0078125f;
    const float var = sq_ * 0.0078125f - mu*mu;
    const float rs  = rsqrtf(var + 1e-5f);
    ep1[s*128+lane]    = (v0-mu)*rs*lng[lane]    + lnb[lane];
    ep1[s*128+64+lane] = (v1-mu)*rs*lng[64+lane] + lnb[64+lane];
  }
  __syncthreads();
  #pragma unroll
  for (int si=0; si<2; ++si){
    const int s = sh + si;
    float a = m1b[d];
    a += dot128(m1w + d*256,       ep1  + s*128);
    a += dot128(m1w + d*256 + 128, srce + s*128);
    ep2[s*128+d] = fmaxf(a, 0.f);
  }
  __syncthreads();
  #pragma unroll
  for (int si=0; si<2; ++si){
    const int s = sh + si;
    out[(size_t)(gsrc0+s)*128 + d] = m2b[d] + dot128(m2w + d*128, ep2 + s*128);
  }
}

extern "C" void kernel_launch(void* const* d_in, const int* in_sizes, int n_in,
                              void* d_out, int out_size, void* d_ws, size_t ws_size,
                              hipStream_t stream){
  const float* src = (const float*)d_in[0];
  const float* ngh = (const float*)d_in[1];
  const float* hid = (const float*)d_in[2];
  const int*   msk = (const int*)  d_in[3];
  const float* wih = (const float*)d_in[4];
  const float* whh = (const float*)d_in[5];
  const float* bih = (const float*)d_in[6];
  const float* bhh = (const float*)d_in[7];
  const float* wqs = (const float*)d_in[8];
  const float* wks = (const float*)d_in[9];
  const float* wvs = (const float*)d_in[10];
  const float* fcw = (const float*)d_in[11];
  const float* fcb = (const float*)d_in[12];
  const float* lng = (const float*)d_in[13];
  const float* lnb = (const float*)d_in[14];
  const float* m1w = (const float*)d_in[15];
  const float* m1b = (const float*)d_in[16];
  const float* m2w = (const float*)d_in[17];
  const float* m2b = (const float*)d_in[18];
  float* out = (float*)d_out;

  unsigned short* wbf = (unsigned short*)d_ws;              // 131072 bf16
  int*   flags = (int*)  ((char*)d_ws + 262144);
  float* q_ws  = (float*)((char*)d_ws + 262400);            // 8192*128 f32

  prep_weights<<<512, 256, 0, stream>>>(wih, whh, wks, wvs, msk, wbf, flags);
  prep_q      <<<256, 128, 0, stream>>>(src, wqs, q_ws);
  cawn_main   <<<2048, 256, 0, stream>>>(src, ngh, hid, msk, bih, bhh,
                                         fcw, fcb, lng, lnb, m1w, m1b, m2w, m2b,
                                         wbf, wbf+49152, wbf+98304, wbf+114688,
                                         q_ws, flags, out);
}

// Round 3
// 689.401 us; speedup vs baseline: 3.9835x; 3.9835x over previous
//
#include <hip/hip_runtime.h>

typedef float  f32x4  __attribute__((ext_vector_type(4)));
typedef short  bf16x8 __attribute__((ext_vector_type(8)));
typedef unsigned short u16x4 __attribute__((ext_vector_type(4)));

#define MFMA16(a,b,c) __builtin_amdgcn_mfma_f32_16x16x32_bf16((a),(b),(c),0,0,0)

__device__ __forceinline__ unsigned short f2bf(float f){
  unsigned u = __float_as_uint(f);
  u += 0x7fffu + ((u>>16)&1u);            // RNE
  return (unsigned short)(u>>16);
}
__device__ __forceinline__ float bf2f(unsigned short u){
  return __uint_as_float(((unsigned)u)<<16);
}
__device__ __forceinline__ float sigm(float x){
  return __fdividef(1.f, 1.f + __expf(-x));
}
__device__ __forceinline__ float tanhfast(float x){
  return 1.f - __fdividef(2.f, __expf(2.f*x) + 1.f);
}
__device__ __forceinline__ float dot128(const float* __restrict__ w, const float* s){
  float a0=0.f,a1=0.f,a2=0.f,a3=0.f;
  #pragma unroll
  for (int e=0;e<32;++e){
    f32x4 w4 = *(const f32x4*)(w + (e<<2));
    f32x4 x4 = *(const f32x4*)(s + (e<<2));
    a0 = fmaf(w4[0],x4[0],a0); a1 = fmaf(w4[1],x4[1],a1);
    a2 = fmaf(w4[2],x4[2],a2); a3 = fmaf(w4[3],x4[3],a3);
  }
  return (a0+a1)+(a2+a3);
}

// ---------------- prep: weights->bf16, M = fc_w_h @ Wv_h, qk = Wk_h^T(Wq_h src) ----------------
__global__ void prep_all(const float* __restrict__ wih, const float* __restrict__ whh,
                         const float* __restrict__ wqs, const float* __restrict__ wks,
                         const float* __restrict__ wvs, const float* __restrict__ fcw,
                         const float* __restrict__ src, const int* __restrict__ mask_i,
                         unsigned short* __restrict__ wbf, float* __restrict__ M_ws,
                         unsigned short* __restrict__ qk_ws, int* __restrict__ flags){
  const int b = blockIdx.x, t = threadIdx.x;
  if (b < 384){
    const int tid = b*256 + t;          // < 98304
    if (tid < 49152) wbf[tid] = f2bf(wih[tid]);
    else             wbf[tid] = f2bf(whh[tid-49152]);
    if (b==0 && t==0){
      int bytemode = 0;
      for (int i=0;i<64;++i){ unsigned v = (unsigned)mask_i[i]; if (v > 1u) bytemode = 1; }
      flags[0] = bytemode;
    }
  } else if (b < 512){
    const int tid = (b-384)*256 + t;    // < 32768 : M[h][d][e]
    const int h = tid>>14, d = (tid>>7)&127, e = tid&127;
    float a = 0.f;
    for (int j=0;j<64;++j)
      a = fmaf(fcw[d*128 + (h<<6) + j], wvs[((h<<6)+j)*128 + e], a);
    M_ws[tid] = a;
  } else {
    __shared__ __align__(16) float sl_src[32*128];
    __shared__ __align__(16) float sl_q[32*128];
    const int blk = b - 512;            // 0..255, 32 sources each
    const size_t s0 = (size_t)blk * 32;
    for (int i=0;i<16;++i) sl_src[t + i*256] = src[s0*128 + t + i*256];
    __syncthreads();
    for (int k=0;k<16;++k){
      const int job = t + k*256, s = job>>7, c = job&127;
      sl_q[job] = dot128(wqs + c*128, sl_src + s*128);
    }
    __syncthreads();
    const int d = t&127, h = (t>>7)&1;
    float acc[32];
    #pragma unroll
    for (int s=0;s<32;++s) acc[s]=0.f;
    for (int j=0;j<64;++j){
      const float wk = wks[((h<<6)+j)*128 + d];
      #pragma unroll
      for (int s=0;s<32;++s) acc[s] = fmaf(wk, sl_q[s*128 + (h<<6) + j], acc[s]);
    }
    for (int s=0;s<32;++s) qk_ws[(s0+s)*256 + (h<<7) + d] = f2bf(acc[s]);
  }
}

// ---------------- main fused kernel: 4 sources per block, 256 threads ----------------
// LDS (56848 B): bufA(x) 16K | bufB(h) 16K | bufC(seq) 16K | qk 1K | sc 0.5K |
//                s_lds 4K | bias 2K | hflag
__global__ __launch_bounds__(256, 2) void cawn_main(
    const float* __restrict__ src, const float* __restrict__ ngh,
    const float* __restrict__ hid, const int* __restrict__ mask_i,
    const float* __restrict__ bih, const float* __restrict__ bhh,
    const float* __restrict__ fcb, const float* __restrict__ lng,
    const float* __restrict__ lnb, const float* __restrict__ m1w,
    const float* __restrict__ m1b, const float* __restrict__ m2w,
    const float* __restrict__ m2b,
    const unsigned short* __restrict__ wihb, const unsigned short* __restrict__ whhb,
    const float* __restrict__ M_ws, const unsigned short* __restrict__ qk_ws,
    const int* __restrict__ flags, float* __restrict__ out)
{
  __shared__ __align__(16) char smem[56848];
  unsigned short* bufA = (unsigned short*)smem;
  unsigned short* bufB = (unsigned short*)(smem + 16384);
  unsigned short* bufC = (unsigned short*)(smem + 32768);
  float* qk_lds = (float*)(smem + 49152);
  float* sc     = (float*)(smem + 50176);
  float* s_lds  = (float*)(smem + 50688);
  float* brz0   = (float*)(smem + 54784);
  float* brz1   = (float*)(smem + 55296);
  float* bin_l  = (float*)(smem + 55808);
  float* bhn_l  = (float*)(smem + 56320);
  int*   hflag  = (int*)  (smem + 56832);

  const int t    = threadIdx.x;
  const int wv   = t >> 6;
  const int lane = t & 63;
  const int l15  = lane & 15;
  const int lgrp = lane >> 4;
  const int gsrc0 = blockIdx.x * 4;
  const int mask_mode = flags[0];
  const int rsw = (l15 & 7) << 3;       // row swizzle for rows rt*16+l15 (low3 = l15&7)
  const f32x4 z4 = {0.f,0.f,0.f,0.f};

  // combined biases -> LDS (covered by first chunk's barrier)
  if (t < 128){
    brz0[t]  = bih[t]     + bhh[t];
    brz1[t]  = bih[128+t] + bhh[128+t];
    bin_l[t] = bih[256+t];
    bhn_l[t] = bhh[256+t];
  }

  // ---- W_ih register-stationary: wave wv owns cols [32wv,32wv+32) of gates r,z,n ----
  bf16x8 Wf[3][2][4];
  #pragma unroll
  for (int g=0; g<3; ++g)
    #pragma unroll
    for (int j=0; j<2; ++j){
      const int nc = (wv<<5) + (j<<4) + l15;
      #pragma unroll
      for (int kb=0; kb<4; ++kb)
        Wf[g][j][kb] = *(const bf16x8*)(wihb + (((g<<7) + nc)<<7) + (kb<<5) + (lgrp<<3));
    }

  for (int sl=0; sl<4; ++sl){
    const int gsrc = gsrc0 + sl;
    const size_t base = (size_t)gsrc * 8192;

    // ---- stage x,h : f32 -> bf16 LDS (XOR-swizzled) ----
    bool hnzl = false;
    #pragma unroll
    for (int it=0; it<8; ++it){
      const int f4  = t + (it<<8);
      const int m   = f4 >> 5;
      const int col = (f4 & 31) << 2;
      f32x4 vx = *(const f32x4*)(ngh + base + (f4<<2));
      f32x4 vh = *(const f32x4*)(hid + base + (f4<<2));
      hnzl = hnzl || (vh[0]!=0.f)||(vh[1]!=0.f)||(vh[2]!=0.f)||(vh[3]!=0.f);
      const int idx = (m<<7) + (col ^ ((m&7)<<3));
      u16x4 px, ph;
      px[0]=f2bf(vx[0]); px[1]=f2bf(vx[1]); px[2]=f2bf(vx[2]); px[3]=f2bf(vx[3]);
      ph[0]=f2bf(vh[0]); ph[1]=f2bf(vh[1]); ph[2]=f2bf(vh[2]); ph[3]=f2bf(vh[3]);
      *(u16x4*)&bufA[idx] = px;
      *(u16x4*)&bufB[idx] = ph;
    }
    qk_lds[t] = bf2f(qk_ws[(size_t)gsrc*256 + t]);
    { unsigned long long b = __ballot((int)hnzl); if (lane==0) hflag[wv] = (b!=0ull)?1:0; }
    __syncthreads();                                  // (1)
    const int hnz = hflag[0] | hflag[1] | hflag[2] | hflag[3];

    // ---- GRU: per row-tile, MFMA + fused elementwise -> seq in bufC ----
    #pragma unroll
    for (int rt=0; rt<4; ++rt){
      const int row = (rt<<4) + l15;
      bf16x8 bx[4];
      #pragma unroll
      for (int kb=0; kb<4; ++kb)
        bx[kb] = *(const bf16x8*)&bufA[(row<<7) + ((((kb<<5)+(lgrp<<3))) ^ rsw)];
      f32x4 ar[2]={z4,z4}, az[2]={z4,z4}, an[2]={z4,z4}, anh[2]={z4,z4};
      #pragma unroll
      for (int j=0; j<2; ++j)
        #pragma unroll
        for (int kb=0; kb<4; ++kb){
          ar[j] = MFMA16(Wf[0][j][kb], bx[kb], ar[j]);
          az[j] = MFMA16(Wf[1][j][kb], bx[kb], az[j]);
          an[j] = MFMA16(Wf[2][j][kb], bx[kb], an[j]);
        }
      if (hnz){   // general-input path: stream W_hh from L2 (short live ranges)
        bf16x8 bh[4];
        #pragma unroll
        for (int kb=0; kb<4; ++kb)
          bh[kb] = *(const bf16x8*)&bufB[(row<<7) + ((((kb<<5)+(lgrp<<3))) ^ rsw)];
        #pragma unroll
        for (int j=0; j<2; ++j){
          const int nc = (wv<<5) + (j<<4) + l15;
          #pragma unroll
          for (int kb=0; kb<4; ++kb){
            bf16x8 ur = *(const bf16x8*)(whhb + ((      nc)<<7)*1 + (((0<<7)+nc)<<7) - (((0<<7)+nc)<<7) + (((0<<7)+nc)<<7) + (kb<<5)+(lgrp<<3));
            ur = *(const bf16x8*)(whhb + (((0<<7)+nc)<<7) + (kb<<5)+(lgrp<<3));
            bf16x8 uz = *(const bf16x8*)(whhb + (((1<<7)+nc)<<7) + (kb<<5)+(lgrp<<3));
            bf16x8 un = *(const bf16x8*)(whhb + (((2<<7)+nc)<<7) + (kb<<5)+(lgrp<<3));
            ar[j]  = MFMA16(ur, bh[kb], ar[j]);
            az[j]  = MFMA16(uz, bh[kb], az[j]);
            anh[j] = MFMA16(un, bh[kb], anh[j]);
          }
        }
      }
      // elementwise -> seq
      #pragma unroll
      for (int j=0; j<2; ++j){
        const int colb = (wv<<5) + (j<<4) + (lgrp<<2);
        const f32x4 b0 = *(const f32x4*)&brz0[colb];
        const f32x4 b1 = *(const f32x4*)&brz1[colb];
        const f32x4 b2 = *(const f32x4*)&bin_l[colb];
        const f32x4 b3 = *(const f32x4*)&bhn_l[colb];
        const int eidx = (row<<7) + (colb ^ rsw);
        const u16x4 hv = *(const u16x4*)&bufB[eidx];
        u16x4 sq;
        #pragma unroll
        for (int i=0; i<4; ++i){
          const float rv = sigm(ar[j][i] + b0[i]);
          const float zv = sigm(az[j][i] + b1[i]);
          const float nv = tanhfast(an[j][i] + b2[i] + rv*(anh[j][i] + b3[i]));
          sq[i] = f2bf((1.f - zv)*nv + zv*bf2f(hv[i]));
        }
        *(u16x4*)&bufC[eidx] = sq;
      }
    }
    __syncthreads();                                  // (2)

    // ---- scores + softmax: wave -> head wv&1 (waves 2,3 redundant), lane = neighbor ----
    {
      const int hh = wv & 1;
      float a = 0.f;
      #pragma unroll
      for (int c8=0; c8<16; ++c8){
        const int cb = c8<<3;
        bf16x8 kc = *(const bf16x8*)&bufC[(lane<<7) + (cb ^ ((lane&7)<<3))];
        #pragma unroll
        for (int u=0; u<8; ++u)
          a = fmaf(bf2f((unsigned short)kc[u]), qk_lds[(hh<<7)+cb+u], a);
      }
      bool msk;
      if (mask_mode == 0) msk = (mask_i[(size_t)gsrc*64 + lane] != 0);
      else                msk = (((const unsigned char*)mask_i)[(size_t)gsrc*64 + lane] != 0);
      float s = msk ? -1e10f : a*0.125f;
      float mx = s;
      #pragma unroll
      for (int o=32;o>=1;o>>=1) mx = fmaxf(mx, __shfl_xor(mx,o));
      const float e = __expf(s - mx);
      float sum = e;
      #pragma unroll
      for (int o=32;o>=1;o>>=1) sum += __shfl_xor(sum,o);
      if (wv < 2) sc[(hh<<6)+lane] = __fdividef(e, sum);
    }
    __syncthreads();                                  // (3)

    // ---- s_h = sum_n attn[h,n]*seq[n]: thread=(j=t>>2 ->(h,quad), sub=t&3 row-quarter) ----
    {
      const int jidx = t>>2, sub = t&3;
      const int hh2 = jidx>>5, quad = jidx&31;
      f32x4 a = z4;
      #pragma unroll
      for (int i=0; i<16; ++i){
        const int rr = (sub<<4) + i;
        const u16x4 sv = *(const u16x4*)&bufC[(rr<<7) + ((quad<<2) ^ ((rr&7)<<3))];
        const float w = sc[(hh2<<6)+rr];
        #pragma unroll
        for (int k=0;k<4;++k) a[k] = fmaf(w, bf2f(sv[k]), a[k]);
      }
      #pragma unroll
      for (int k=0;k<4;++k) a[k] += __shfl_xor(a[k],1);
      #pragma unroll
      for (int k=0;k<4;++k) a[k] += __shfl_xor(a[k],2);
      if (sub == 0)
        *(f32x4*)&s_lds[(((sl<<1)+hh2)<<7) + (quad<<2)] = a;
    }
    __syncthreads();                                  // (4)
  }

  // ---------------- epilogue: attnfc via M_h, +res, LN, merge MLP ----------------
  float* ep1  = (float*)smem;            // [4][128]
  float* ep2  = (float*)(smem + 2048);   // [4][128]
  float* srce = (float*)(smem + 16384);  // [4][128]
  srce[t]     = src[(size_t)gsrc0*128 + t];
  srce[t+256] = src[(size_t)gsrc0*128 + t + 256];
  __syncthreads();

  const int d  = t & 127;
  const int sh = (t >> 7) << 1;
  #pragma unroll
  for (int si=0; si<2; ++si){
    const int s = sh + si;
    float a = fcb[d];
    a += dot128(M_ws +          d*128, &s_lds[((s<<1)  )<<7]);
    a += dot128(M_ws + 16384 + d*128, &s_lds[((s<<1)+1)<<7]);
    ep1[s*128+d] = a + srce[s*128+d];
  }
  __syncthreads();
  {
    const int s = wv;
    const float v0 = ep1[s*128+lane], v1 = ep1[s*128+64+lane];
    float sum = v0+v1, sq_ = v0*v0 + v1*v1;
    #pragma unroll
    for (int o=32;o>=1;o>>=1){ sum += __shfl_xor(sum,o); sq_ += __shfl_xor(sq_,o); }
    const float mu  = sum * 0.0078125f;
    const float var = sq_ * 0.0078125f - mu*mu;
    const float rs  = rsqrtf(var + 1e-5f);
    ep1[s*128+lane]    = (v0-mu)*rs*lng[lane]    + lnb[lane];
    ep1[s*128+64+lane] = (v1-mu)*rs*lng[64+lane] + lnb[64+lane];
  }
  __syncthreads();
  #pragma unroll
  for (int si=0; si<2; ++si){
    const int s = sh + si;
    float a = m1b[d];
    a += dot128(m1w + d*256,       ep1  + s*128);
    a += dot128(m1w + d*256 + 128, srce + s*128);
    ep2[s*128+d] = fmaxf(a, 0.f);
  }
  __syncthreads();
  #pragma unroll
  for (int si=0; si<2; ++si){
    const int s = sh + si;
    out[(size_t)(gsrc0+s)*128 + d] = m2b[d] + dot128(m2w + d*128, ep2 + s*128);
  }
}

extern "C" void kernel_launch(void* const* d_in, const int* in_sizes, int n_in,
                              void* d_out, int out_size, void* d_ws, size_t ws_size,
                              hipStream_t stream){
  const float* src = (const float*)d_in[0];
  const float* ngh = (const float*)d_in[1];
  const float* hid = (const float*)d_in[2];
  const int*   msk = (const int*)  d_in[3];
  const float* wih = (const float*)d_in[4];
  const float* whh = (const float*)d_in[5];
  const float* bih = (const float*)d_in[6];
  const float* bhh = (const float*)d_in[7];
  const float* wqs = (const float*)d_in[8];
  const float* wks = (const float*)d_in[9];
  const float* wvs = (const float*)d_in[10];
  const float* fcw = (const float*)d_in[11];
  const float* fcb = (const float*)d_in[12];
  const float* lng = (const float*)d_in[13];
  const float* lnb = (const float*)d_in[14];
  const float* m1w = (const float*)d_in[15];
  const float* m1b = (const float*)d_in[16];
  const float* m2w = (const float*)d_in[17];
  const float* m2b = (const float*)d_in[18];
  float* out = (float*)d_out;

  unsigned short* wbf   = (unsigned short*)d_ws;                 // 98304 bf16 = 196608 B
  int*            flags = (int*)((char*)d_ws + 196608);          // 64 B
  float*          M_ws  = (float*)((char*)d_ws + 196672);        // 32768 f32 = 131072 B
  unsigned short* qk_ws = (unsigned short*)((char*)d_ws + 327744); // 8192*256 bf16 = 4 MB

  prep_all <<<768, 256, 0, stream>>>(wih, whh, wqs, wks, wvs, fcw, src, msk,
                                     wbf, M_ws, qk_ws, flags);
  cawn_main<<<2048, 256, 0, stream>>>(src, ngh, hid, msk, bih, bhh,
                                      fcb, lng, lnb, m1w, m1b, m2w, m2b,
                                      wbf, wbf + 49152, M_ws, qk_ws, flags, out);
}

// Round 4
// 456.263 us; speedup vs baseline: 6.0190x; 1.5110x over previous
//
#include <hip/hip_runtime.h>

typedef float  f32x4  __attribute__((ext_vector_type(4)));
typedef short  bf16x8 __attribute__((ext_vector_type(8)));
typedef unsigned short u16x4 __attribute__((ext_vector_type(4)));

typedef const __attribute__((address_space(1))) unsigned int* gas_u32;
typedef __attribute__((address_space(3))) unsigned int* las_u32;

#define MFMA16(a,b,c) __builtin_amdgcn_mfma_f32_16x16x32_bf16((a),(b),(c),0,0,0)

__device__ __forceinline__ unsigned short f2bf(float f){
  unsigned u = __float_as_uint(f);
  u += 0x7fffu + ((u>>16)&1u);            // RNE
  return (unsigned short)(u>>16);
}
__device__ __forceinline__ float bf2f(unsigned short u){
  return __uint_as_float(((unsigned)u)<<16);
}
__device__ __forceinline__ float sigm(float x){
  return __fdividef(1.f, 1.f + __expf(-x));
}
__device__ __forceinline__ float tanhfast(float x){
  return 1.f - __fdividef(2.f, __expf(2.f*x) + 1.f);
}
__device__ __forceinline__ float dot128(const float* __restrict__ w, const float* s){
  float a0=0.f,a1=0.f,a2=0.f,a3=0.f;
  #pragma unroll
  for (int e=0;e<32;++e){
    f32x4 w4 = *(const f32x4*)(w + (e<<2));
    f32x4 x4 = *(const f32x4*)(s + (e<<2));
    a0 = fmaf(w4[0],x4[0],a0); a1 = fmaf(w4[1],x4[1],a1);
    a2 = fmaf(w4[2],x4[2],a2); a3 = fmaf(w4[3],x4[3],a3);
  }
  return (a0+a1)+(a2+a3);
}
// pack 8 f32 -> bf16x8 via v_cvt_pk_bf16_f32 (T12 primitive)
__device__ __forceinline__ bf16x8 cvt8(const f32x4 a, const f32x4 b){
  union { int i[4]; bf16x8 v; } u;
  asm("v_cvt_pk_bf16_f32 %0, %1, %2" : "=v"(u.i[0]) : "v"(a[0]), "v"(a[1]));
  asm("v_cvt_pk_bf16_f32 %0, %1, %2" : "=v"(u.i[1]) : "v"(a[2]), "v"(a[3]));
  asm("v_cvt_pk_bf16_f32 %0, %1, %2" : "=v"(u.i[2]) : "v"(b[0]), "v"(b[1]));
  asm("v_cvt_pk_bf16_f32 %0, %1, %2" : "=v"(u.i[3]) : "v"(b[2]), "v"(b[3]));
  return u.v;
}
// f32-tile element xor (32B granule + row bit3) and seq bf16 element xor
__device__ __forceinline__ int swx(int m){ return (((m&7)<<1) | ((m>>3)&1)) << 2; }
__device__ __forceinline__ int sws(int m){ return ((m&7)<<3) | (((m>>3)&1)<<6); }

// LDS map (59904 B)
#define XB_OFF   0        // 4 ring bufs x 16 rows x 128 f32 (8192 B each)
#define SEQ_OFF  32768    // 64x128 bf16
#define QK_OFF   49152    // [4][256] f32
#define SC_OFF   53248    // [2][64] f32
#define SH_OFF   53760    // [4][2][128] f32
#define BIAS_OFF 57856    // brz0,brz1,bin,bhn f32[128] each
#define SMEM_SZ  59904

// =================== prep: everything streaming, one kernel ===================
__global__ void prep_all(const float* __restrict__ wih, const float* __restrict__ whh,
                         const float* __restrict__ wqs, const float* __restrict__ wks,
                         const float* __restrict__ wvs, const float* __restrict__ fcw,
                         const float* __restrict__ src, const int* __restrict__ mask_i,
                         const float* __restrict__ hid,
                         unsigned short* __restrict__ wbf, float* __restrict__ M_ws,
                         unsigned short* __restrict__ qk_ws,
                         unsigned long long* __restrict__ mask_bits,
                         int* __restrict__ flags){
  __shared__ __align__(16) float sl_src[32*128];
  __shared__ __align__(16) float sl_q[32*128];
  const int b = blockIdx.x, t = threadIdx.x;
  if (b < 384){                       // weights -> bf16
    const int tid = b*256 + t;
    if (tid < 49152) wbf[tid] = f2bf(wih[tid]);
    else             wbf[tid] = f2bf(whh[tid-49152]);
  } else if (b < 512){                // M[h][d][e] = fc_w_h @ Wv_h
    const int tid = (b-384)*256 + t;
    const int h = tid>>14, d = (tid>>7)&127, e = tid&127;
    float a = 0.f;
    for (int j=0;j<64;++j)
      a = fmaf(fcw[d*128 + (h<<6) + j], wvs[((h<<6)+j)*128 + e], a);
    M_ws[tid] = a;
  } else if (b < 768){                // qk = Wk_h^T (Wq_h src)
    const int blk = b - 512;
    const size_t s0 = (size_t)blk * 32;
    for (int i=0;i<16;++i) sl_src[t + i*256] = src[s0*128 + t + i*256];
    __syncthreads();
    for (int k=0;k<16;++k){
      const int job = t + k*256, s = job>>7, c = job&127;
      sl_q[job] = dot128(wqs + c*128, sl_src + s*128);
    }
    __syncthreads();
    const int d = t&127, h = (t>>7)&1;
    float acc[32];
    #pragma unroll
    for (int s=0;s<32;++s) acc[s]=0.f;
    for (int j=0;j<64;++j){
      const float wk = wks[((h<<6)+j)*128 + d];
      #pragma unroll
      for (int s=0;s<32;++s) acc[s] = fmaf(wk, sl_q[s*128 + (h<<6) + j], acc[s]);
    }
    for (int s=0;s<32;++s) qk_ws[(s0+s)*256 + (h<<7) + d] = f2bf(acc[s]);
  } else if (b < 2816){               // mask -> 64-bit masks (self-probing dtype)
    const int blk = b - 768;
    const int wv = t>>6, lane = t&63;
    const int gsrc = blk*4 + wv;
    const unsigned v = (unsigned)mask_i[(size_t)gsrc*64 + lane];
    const int bytemode = __any((int)(v > 1u));
    bool bit;
    if (bytemode) bit = (((const unsigned char*)mask_i)[(size_t)gsrc*64 + lane] != 0);
    else          bit = (v != 0u);
    const unsigned long long bits = __ballot((int)bit);
    if (lane == 0) mask_bits[gsrc] = bits;
  } else {                            // hid zero scan (256 MB stream)
    const size_t blk = b - 2816;
    bool nz = false;
    #pragma unroll 4
    for (int it=0; it<32; ++it){
      const size_t idx = blk*8192 + (size_t)it*256 + t;   // f32x4 units
      const f32x4 v = *(const f32x4*)(hid + idx*4);
      nz = nz || (v[0]!=0.f)||(v[1]!=0.f)||(v[2]!=0.f)||(v[3]!=0.f);
    }
    if (__ballot((int)nz)){ if ((t&63)==0) atomicOr(flags+1, 1); }
  }
}

// ---- shared attention tail: scores -> softmax -> PV (writes sH[srcI]) ----
__device__ __forceinline__ void scores_pv(char* smem, int srcI, unsigned long long mb,
                                          int wv, int lane){
  const unsigned short* seq = (const unsigned short*)(smem + SEQ_OFF);
  const float* qk_lds = (const float*)(smem + QK_OFF);
  float* sc = (float*)(smem + SC_OFF);
  float* sH = (float*)(smem + SH_OFF);
  {
    const int hh = wv & 1;
    const float* qrow = qk_lds + (srcI<<8) + (hh<<7);
    float a = 0.f;
    #pragma unroll
    for (int c8=0; c8<16; ++c8){
      const int cb = c8<<3;
      bf16x8 kc = *(const bf16x8*)&seq[(lane<<7) + (cb ^ sws(lane))];
      #pragma unroll
      for (int u=0;u<8;++u) a = fmaf(bf2f((unsigned short)kc[u]), qrow[cb+u], a);
    }
    float s = ((mb>>lane)&1ull) ? -1e10f : a*0.125f;
    float mx = s;
    #pragma unroll
    for (int o=32;o>=1;o>>=1) mx = fmaxf(mx, __shfl_xor(mx,o));
    const float e = __expf(s - mx);
    float sum = e;
    #pragma unroll
    for (int o=32;o>=1;o>>=1) sum += __shfl_xor(sum,o);
    if (wv < 2) sc[(hh<<6)+lane] = __fdividef(e, sum);
  }
  asm volatile("s_waitcnt lgkmcnt(0)" ::: "memory");
  __builtin_amdgcn_sched_barrier(0);
  __builtin_amdgcn_s_barrier();
  {
    const int tt = (wv<<6)+lane;
    const int jidx = tt>>2, sub = tt&3;
    const int hh2 = jidx>>5, quad = jidx&31;
    f32x4 a = {0.f,0.f,0.f,0.f};
    #pragma unroll
    for (int i=0;i<16;++i){
      const int rr = (sub<<4)+i;
      const u16x4 sv = *(const u16x4*)&seq[(rr<<7) + ((quad<<2) ^ sws(rr))];
      const float w = sc[(hh2<<6)+rr];
      #pragma unroll
      for (int k=0;k<4;++k) a[k] = fmaf(w, bf2f(sv[k]), a[k]);
    }
    #pragma unroll
    for (int k=0;k<4;++k) a[k] += __shfl_xor(a[k],1);
    #pragma unroll
    for (int k=0;k<4;++k) a[k] += __shfl_xor(a[k],2);
    if (sub == 0)
      *(f32x4*)&sH[(((srcI<<1)+hh2)<<7) + (quad<<2)] = a;
  }
}

// =================== main fused kernel: 4 sources / block ===================
__global__ __attribute__((amdgpu_flat_work_group_size(256,256)))
           __attribute__((amdgpu_waves_per_eu(2)))
void cawn_main(
    const float* __restrict__ src, const float* __restrict__ ngh,
    const float* __restrict__ hid,
    const float* __restrict__ bih, const float* __restrict__ bhh,
    const float* __restrict__ fcb, const float* __restrict__ lng,
    const float* __restrict__ lnb, const float* __restrict__ m1w,
    const float* __restrict__ m1b, const float* __restrict__ m2w,
    const float* __restrict__ m2b,
    const unsigned short* __restrict__ wihb, const unsigned short* __restrict__ whhb,
    const float* __restrict__ M_ws, const unsigned short* __restrict__ qk_ws,
    const unsigned long long* __restrict__ mask_bits,
    const int* __restrict__ flags, float* __restrict__ out)
{
  __shared__ __align__(16) char smem[SMEM_SZ];
  float* qk_lds = (float*)(smem + QK_OFF);
  float* brz0   = (float*)(smem + BIAS_OFF);
  float* brz1   = (float*)(smem + BIAS_OFF + 512);
  float* bin_l  = (float*)(smem + BIAS_OFF + 1024);
  float* bhn_l  = (float*)(smem + BIAS_OFF + 1536);
  unsigned short* seq = (unsigned short*)(smem + SEQ_OFF);

  const int t    = threadIdx.x;
  const int wv   = t >> 6;
  const int lane = t & 63;
  const int l15  = lane & 15;
  const int lgrp = lane >> 4;
  const int gsrc0 = blockIdx.x * 4;
  const f32x4 z4 = {0.f,0.f,0.f,0.f};
  const int hz = flags[1];

  // biases + qk -> LDS (visible after first barrier)
  if (t < 128){
    brz0[t]  = bih[t]     + bhh[t];
    brz1[t]  = bih[128+t] + bhh[128+t];
    bin_l[t] = bih[256+t];
    bhn_l[t] = bhh[256+t];
  }
  #pragma unroll
  for (int s=0;s<4;++s)
    qk_lds[(s<<8)+t] = bf2f(qk_ws[(size_t)(gsrc0+s)*256 + t]);
  const unsigned long long mb0 = mask_bits[gsrc0];
  const unsigned long long mb1 = mask_bits[gsrc0+1];
  const unsigned long long mb2 = mask_bits[gsrc0+2];
  const unsigned long long mb3 = mask_bits[gsrc0+3];

  if (!hz){
    // ---------------- FAST PATH: h == 0, async-pipelined ----------------
    // W_ih register-stationary: wave wv owns cols [32wv,32wv+32) of r,z,n
    bf16x8 Wf[3][2][4];
    #pragma unroll
    for (int g=0; g<3; ++g)
      #pragma unroll
      for (int j=0; j<2; ++j){
        const int nc = (wv<<5) + (j<<4) + l15;
        #pragma unroll
        for (int kb=0; kb<4; ++kb)
          Wf[g][j][kb] = *(const bf16x8*)(wihb + (((g<<7) + nc)<<7) + (kb<<5) + (lgrp<<3));
      }

    // issue one 16-row stage (2 x global_load_lds dwordx4 per thread)
    auto issue = [&](int kk){
      const int srcI = kk>>2, stg = kk&3;
      const size_t base = (size_t)(gsrc0+srcI)*8192 + (size_t)stg*2048; // f32 units
      #pragma unroll
      for (int r=0;r<2;++r){
        const int rl = (wv<<2) + (r<<1) + (lane>>5);
        const int s16 = (lane&31) ^ (((rl&7)<<1) | ((rl>>3)&1));
        const float* g = ngh + base + (rl<<7) + (s16<<2);
        char* l = smem + XB_OFF + (kk&3)*8192 + (((wv<<2)+(r<<1))<<9);
        __builtin_amdgcn_global_load_lds((gas_u32)g, (las_u32)l, 16, 0, 0);
      }
    };
    issue(0); issue(1);

    for (int k=0;k<16;++k){
      if (k < 14) issue(k+2);
      if (k < 14)      asm volatile("s_waitcnt vmcnt(4) lgkmcnt(0)" ::: "memory");
      else if (k==14)  asm volatile("s_waitcnt vmcnt(2) lgkmcnt(0)" ::: "memory");
      else             asm volatile("s_waitcnt vmcnt(0) lgkmcnt(0)" ::: "memory");
      __builtin_amdgcn_sched_barrier(0);
      __builtin_amdgcn_s_barrier();

      const int srcI = k>>2, stg = k&3;
      // fragments from f32 tile (swizzled) -> bf16
      const float* xrow = (const float*)(smem + XB_OFF + (k&3)*8192) + (l15<<7);
      const int sw = swx(l15);
      bf16x8 bx[4];
      #pragma unroll
      for (int kb=0;kb<4;++kb){
        const int c0 = (kb<<5) + (lgrp<<3);
        const f32x4 u0 = *(const f32x4*)&xrow[c0 ^ sw];
        const f32x4 u1 = *(const f32x4*)&xrow[(c0+4) ^ sw];
        bx[kb] = cvt8(u0,u1);
      }
      f32x4 ar[2]={z4,z4}, az[2]={z4,z4}, an[2]={z4,z4};
      #pragma unroll
      for (int j=0;j<2;++j)
        #pragma unroll
        for (int kb=0;kb<4;++kb){
          ar[j] = MFMA16(Wf[0][j][kb], bx[kb], ar[j]);
          az[j] = MFMA16(Wf[1][j][kb], bx[kb], az[j]);
          an[j] = MFMA16(Wf[2][j][kb], bx[kb], an[j]);
        }
      // elementwise (h=0) -> seq
      const int mrow = (stg<<4) + l15;
      #pragma unroll
      for (int j=0;j<2;++j){
        const int colb = (wv<<5) + (j<<4) + (lgrp<<2);
        const f32x4 b0 = *(const f32x4*)&brz0[colb];
        const f32x4 b1 = *(const f32x4*)&brz1[colb];
        const f32x4 b2 = *(const f32x4*)&bin_l[colb];
        const f32x4 b3 = *(const f32x4*)&bhn_l[colb];
        u16x4 sq;
        #pragma unroll
        for (int i=0;i<4;++i){
          const float rv = sigm(ar[j][i] + b0[i]);
          const float zv = sigm(az[j][i] + b1[i]);
          const float nv = tanhfast(an[j][i] + b2[i] + rv*b3[i]);
          sq[i] = f2bf((1.f - zv)*nv);
        }
        *(u16x4*)&seq[(mrow<<7) + (colb ^ sws(mrow))] = sq;
      }

      if (stg == 3){
        asm volatile("s_waitcnt lgkmcnt(0)" ::: "memory");
        __builtin_amdgcn_sched_barrier(0);
        __builtin_amdgcn_s_barrier();
        const unsigned long long mb = (srcI==0)?mb0:(srcI==1)?mb1:(srcI==2)?mb2:mb3;
        scores_pv(smem, srcI, mb, wv, lane);
      }
    }
  } else {
    // ---------------- SLOW PATH (general h): correct, unpipelined ----------------
    float* xb0 = (float*)(smem + XB_OFF);
    float* xb1 = (float*)(smem + XB_OFF + 8192);
    for (int srcI=0;srcI<4;++srcI){
      const int gsrc = gsrc0+srcI;
      for (int stg=0;stg<4;++stg){
        #pragma unroll
        for (int it=0; it<2; ++it){
          const int f = t + (it<<8);
          const int m = f>>5, c0 = (f&31)<<2;
          const int sw = swx(m);
          const size_t gb = (size_t)gsrc*8192 + stg*2048 + (m<<7) + c0;
          *(f32x4*)&xb0[(m<<7)+(c0^sw)] = *(const f32x4*)(ngh+gb);
          *(f32x4*)&xb1[(m<<7)+(c0^sw)] = *(const f32x4*)(hid+gb);
        }
        __syncthreads();
        const float* xrow = xb0 + (l15<<7);
        const float* hrow = xb1 + (l15<<7);
        const int sw = swx(l15);
        bf16x8 bx[4], bh[4];
        #pragma unroll
        for (int kb=0;kb<4;++kb){
          const int c0 = (kb<<5) + (lgrp<<3);
          bx[kb] = cvt8(*(const f32x4*)&xrow[c0 ^ sw], *(const f32x4*)&xrow[(c0+4) ^ sw]);
          bh[kb] = cvt8(*(const f32x4*)&hrow[c0 ^ sw], *(const f32x4*)&hrow[(c0+4) ^ sw]);
        }
        f32x4 ar[2]={z4,z4}, az[2]={z4,z4}, an[2]={z4,z4}, anh[2]={z4,z4};
        #pragma unroll
        for (int j=0;j<2;++j){
          const int nc = (wv<<5)+(j<<4)+l15;
          #pragma unroll
          for (int kb=0;kb<4;++kb){
            const int ko=(kb<<5)+(lgrp<<3);
            bf16x8 w0 = *(const bf16x8*)(wihb + ((      nc)<<7) + ko);
            bf16x8 w1 = *(const bf16x8*)(wihb + (((128)+nc)<<7) + ko);
            bf16x8 w2 = *(const bf16x8*)(wihb + (((256)+nc)<<7) + ko);
            ar[j] = MFMA16(w0, bx[kb], ar[j]);
            az[j] = MFMA16(w1, bx[kb], az[j]);
            an[j] = MFMA16(w2, bx[kb], an[j]);
            bf16x8 u0 = *(const bf16x8*)(whhb + ((      nc)<<7) + ko);
            bf16x8 u1 = *(const bf16x8*)(whhb + (((128)+nc)<<7) + ko);
            bf16x8 u2 = *(const bf16x8*)(whhb + (((256)+nc)<<7) + ko);
            ar[j]  = MFMA16(u0, bh[kb], ar[j]);
            az[j]  = MFMA16(u1, bh[kb], az[j]);
            anh[j] = MFMA16(u2, bh[kb], anh[j]);
          }
        }
        const int mrow = (stg<<4) + l15;
        #pragma unroll
        for (int j=0;j<2;++j){
          const int colb = (wv<<5) + (j<<4) + (lgrp<<2);
          const f32x4 b0 = *(const f32x4*)&brz0[colb];
          const f32x4 b1 = *(const f32x4*)&brz1[colb];
          const f32x4 b2 = *(const f32x4*)&bin_l[colb];
          const f32x4 b3 = *(const f32x4*)&bhn_l[colb];
          const f32x4 hv = *(const f32x4*)&hrow[colb ^ sw];
          u16x4 sq;
          #pragma unroll
          for (int i=0;i<4;++i){
            const float rv = sigm(ar[j][i] + b0[i]);
            const float zv = sigm(az[j][i] + b1[i]);
            const float nv = tanhfast(an[j][i] + b2[i] + rv*(anh[j][i] + b3[i]));
            sq[i] = f2bf((1.f - zv)*nv + zv*hv[i]);
          }
          *(u16x4*)&seq[(mrow<<7) + (colb ^ sws(mrow))] = sq;
        }
        __syncthreads();
      }
      const unsigned long long mb = (srcI==0)?mb0:(srcI==1)?mb1:(srcI==2)?mb2:mb3;
      scores_pv(smem, srcI, mb, wv, lane);
      __syncthreads();
    }
  }

  // ---------------- epilogue: M-matvec + res + LN + merge MLP ----------------
  __syncthreads();
  float* ep1  = (float*)smem;            // [4][128]
  float* ep2  = (float*)(smem + 2048);   // [4][128]
  float* srce = (float*)(smem + 4096);   // [4][128]
  float* sH   = (float*)(smem + SH_OFF);
  srce[t]     = src[(size_t)gsrc0*128 + t];
  srce[t+256] = src[(size_t)gsrc0*128 + t + 256];
  __syncthreads();

  const int d  = t & 127;
  const int sh = (t >> 7) << 1;
  #pragma unroll
  for (int si=0; si<2; ++si){
    const int s = sh + si;
    float a = fcb[d];
    a += dot128(M_ws +         d*128, &sH[((s<<1)  )<<7]);
    a += dot128(M_ws + 16384 + d*128, &sH[((s<<1)+1)<<7]);
    ep1[s*128+d] = a + srce[s*128+d];
  }
  __syncthreads();
  {
    const int s = wv;
    const float v0 = ep1[s*128+lane], v1 = ep1[s*128+64+lane];
    float sum = v0+v1, sq_ = v0*v0 + v1*v1;
    #pragma unroll
    for (int o=32;o>=1;o>>=1){ sum += __shfl_xor(sum,o); sq_ += __shfl_xor(sq_,o); }
    const float mu  = sum * 0.0078125f;
    const float var = sq_ * 0.0078125f - mu*mu;
    const float rs  = rsqrtf(var + 1e-5f);
    ep1[s*128+lane]    = (v0-mu)*rs*lng[lane]    + lnb[lane];
    ep1[s*128+64+lane] = (v1-mu)*rs*lng[64+lane] + lnb[64+lane];
  }
  __syncthreads();
  #pragma unroll
  for (int si=0; si<2; ++si){
    const int s = sh + si;
    float a = m1b[d];
    a += dot128(m1w + d*256,       ep1  + s*128);
    a += dot128(m1w + d*256 + 128, srce + s*128);
    ep2[s*128+d] = fmaxf(a, 0.f);
  }
  __syncthreads();
  #pragma unroll
  for (int si=0; si<2; ++si){
    const int s = sh + si;
    out[(size_t)(gsrc0+s)*128 + d] = m2b[d] + dot128(m2w + d*128, ep2 + s*128);
  }
}

extern "C" void kernel_launch(void* const* d_in, const int* in_sizes, int n_in,
                              void* d_out, int out_size, void* d_ws, size_t ws_size,
                              hipStream_t stream){
  const float* src = (const float*)d_in[0];
  const float* ngh = (const float*)d_in[1];
  const float* hid = (const float*)d_in[2];
  const int*   msk = (const int*)  d_in[3];
  const float* wih = (const float*)d_in[4];
  const float* whh = (const float*)d_in[5];
  const float* bih = (const float*)d_in[6];
  const float* bhh = (const float*)d_in[7];
  const float* wqs = (const float*)d_in[8];
  const float* wks = (const float*)d_in[9];
  const float* wvs = (const float*)d_in[10];
  const float* fcw = (const float*)d_in[11];
  const float* fcb = (const float*)d_in[12];
  const float* lng = (const float*)d_in[13];
  const float* lnb = (const float*)d_in[14];
  const float* m1w = (const float*)d_in[15];
  const float* m1b = (const float*)d_in[16];
  const float* m2w = (const float*)d_in[17];
  const float* m2b = (const float*)d_in[18];
  float* out = (float*)d_out;

  unsigned short* wbf   = (unsigned short*)d_ws;                   // 196608 B
  int*            flags = (int*)((char*)d_ws + 196608);            // 64 B
  float*          M_ws  = (float*)((char*)d_ws + 196672);          // 131072 B
  unsigned short* qk_ws = (unsigned short*)((char*)d_ws + 327744); // 4 MB
  unsigned long long* mask_bits = (unsigned long long*)((char*)d_ws + 4522048); // 64 KB

  hipMemsetAsync((char*)d_ws + 196608, 0, 64, stream);
  prep_all <<<4864, 256, 0, stream>>>(wih, whh, wqs, wks, wvs, fcw, src, msk, hid,
                                      wbf, M_ws, qk_ws, mask_bits, flags);
  cawn_main<<<2048, 256, 0, stream>>>(src, ngh, hid, bih, bhh,
                                      fcb, lng, lnb, m1w, m1b, m2w, m2b,
                                      wbf, wbf + 49152, M_ws, qk_ws,
                                      mask_bits, flags, out);
}